// Round 1
// baseline (330.753 us; speedup 1.0000x reference)
//
#include <hip/hip_runtime.h>
#include <hip/hip_bf16.h>

#define DD   128
#define CC   16
#define NS   1600
#define QQ   32768
#define HIDN 128

// ---------------------------------------------------------------------------
// Kernel 1: class centers.  grid=16 (one block per class), block=512 (128 d x 4 slices)
// sg[c][d]    = sigmoid(mean(support_feat_inv | label==c))
// pre_s[c][d] = mean(support_features | label==c)
// ---------------------------------------------------------------------------
__global__ __launch_bounds__(512) void centers_kernel(
    const float* __restrict__ sfi, const float* __restrict__ sf,
    const int* __restrict__ labels, float* __restrict__ sg,
    float* __restrict__ pre_s) {
  const int c = blockIdx.x;
  const int d = threadIdx.x & 127;
  const int s = threadIdx.x >> 7;  // 0..3
  float a = 0.f, b = 0.f, cnt = 0.f;
  const int i0 = s * (NS / 4), i1 = i0 + (NS / 4);
  for (int i = i0; i < i1; ++i) {
    if (labels[i] == c) {
      a += sfi[i * DD + d];
      b += sf[i * DD + d];
      cnt += 1.f;
    }
  }
  __shared__ float A[4][128], B[4][128], CNTs[4];
  A[s][d] = a;
  B[s][d] = b;
  if (d == 0) CNTs[s] = cnt;
  __syncthreads();
  if (s == 0) {
    a = A[0][d] + A[1][d] + A[2][d] + A[3][d];
    b = B[0][d] + B[1][d] + B[2][d] + B[3][d];
    cnt = CNTs[0] + CNTs[1] + CNTs[2] + CNTs[3];
    cnt = fmaxf(cnt, 1.f);
    float mean = a / cnt;
    sg[c * DD + d] = 1.f / (1.f + expf(-mean));
    pre_s[c * DD + d] = b / cnt;
  }
}

// ---------------------------------------------------------------------------
// Kernel 2: fused per-class weights
// Wt[c][e][j] = W1[e][j] + sg[c][e]*W1[128+e][j] + pre_s[c][e]*W1[256][j]
// grid=(128,16), block=128
// ---------------------------------------------------------------------------
__global__ __launch_bounds__(128) void build_wt_kernel(
    const float* __restrict__ W1, const float* __restrict__ sg,
    const float* __restrict__ pre_s, float* __restrict__ Wt) {
  const int e = blockIdx.x, c = blockIdx.y, j = threadIdx.x;
  const float s = sg[c * DD + e];
  const float p = pre_s[c * DD + e];
  float v = W1[e * HIDN + j] + s * W1[(DD + e) * HIDN + j] + p * W1[2 * DD * HIDN + j];
  Wt[((c * DD) + e) * HIDN + j] = v;
}

// ---------------------------------------------------------------------------
// Kernel 3: main fused kernel.
// Block = 256 threads, 128 queries/block, grid = 256 blocks.
// Thread (qi,jt): qi=tid>>4 owns q=qi*8..+7 ; jt=tid&15 owns j={jt*4..+3, 64+jt*4..+3}
// Per class: h = relu(q @ Wt[c] + b1); w = sigmoid(h . W2 + b2) (shfl-reduce over jt);
// accumulate S[q] += w and sgw[q][e-slice] += w * sg[c][e].
// Epilogue: out[d<64]  = 0.5*(qf[2d]+qf[2d+1])*S + qf[d]
//           out[d>=64] = 0.5*(qf[e]*sgw[e] + qf[e+1]*sgw[e+1]) + qf[d], e=2(d-64)
// ---------------------------------------------------------------------------
__global__ __launch_bounds__(256, 1) void main_kernel(
    const float* __restrict__ qf, const float* __restrict__ Wt,
    const float* __restrict__ sg, const float* __restrict__ b1,
    const float* __restrict__ W2, const float* __restrict__ b2,
    float* __restrict__ out) {
  __shared__ __align__(16) float qT[128][128];  // [e][q]  64 KiB
  __shared__ __align__(16) float Wl[128][128];  // [e][j]  64 KiB

  const int tid = threadIdx.x;
  const int qi = tid >> 4;   // 0..15 -> q block of 8
  const int jt = tid & 15;   // 0..15 -> j slots
  const int qbase = blockIdx.x * 128;

  // ---- stage qT (transposed query tile) ----
  {
    const int q0 = tid >> 5;  // 0..7
    const int ec = tid & 31;  // 0..31 (e-chunk of 4)
    for (int it = 0; it < 16; ++it) {
      int q = it * 8 + q0;
      float4 v = *(const float4*)(qf + (size_t)(qbase + q) * DD + ec * 4);
      qT[ec * 4 + 0][q] = v.x;
      qT[ec * 4 + 1][q] = v.y;
      qT[ec * 4 + 2][q] = v.z;
      qT[ec * 4 + 3][q] = v.w;
    }
  }

  // ---- per-thread constants ----
  float4 b1a = *(const float4*)(b1 + jt * 4);
  float4 b1b = *(const float4*)(b1 + 64 + jt * 4);
  float4 w2a = *(const float4*)(W2 + jt * 4);
  float4 w2b = *(const float4*)(W2 + 64 + jt * 4);
  const float b1v[8] = {b1a.x, b1a.y, b1a.z, b1a.w, b1b.x, b1b.y, b1b.z, b1b.w};
  const float w2v[8] = {w2a.x, w2a.y, w2a.z, w2a.w, w2b.x, w2b.y, w2b.z, w2b.w};
  const float b2s = b2[0];

  float S[8];
  float sgw[8][8];
#pragma unroll
  for (int q = 0; q < 8; ++q) {
    S[q] = 0.f;
#pragma unroll
    for (int k = 0; k < 8; ++k) sgw[q][k] = 0.f;
  }

  for (int c = 0; c < CC; ++c) {
    __syncthreads();  // protect Wl (and first-iter qT) before restage
    {
      const float4* Wg = (const float4*)(Wt + c * DD * HIDN);
      float4* Wd = (float4*)(&Wl[0][0]);
      for (int it = 0; it < 16; ++it) Wd[it * 256 + tid] = Wg[it * 256 + tid];
    }
    __syncthreads();

    float acc[8][8];
#pragma unroll
    for (int q = 0; q < 8; ++q)
#pragma unroll
      for (int k = 0; k < 8; ++k) acc[q][k] = 0.f;

#pragma unroll 2
    for (int e = 0; e < DD; ++e) {
      float4 qa = *(const float4*)(&qT[e][qi * 8]);
      float4 qb = *(const float4*)(&qT[e][qi * 8 + 4]);
      float4 wa = *(const float4*)(&Wl[e][jt * 4]);
      float4 wb = *(const float4*)(&Wl[e][64 + jt * 4]);
      const float qv[8] = {qa.x, qa.y, qa.z, qa.w, qb.x, qb.y, qb.z, qb.w};
      const float wv[8] = {wa.x, wa.y, wa.z, wa.w, wb.x, wb.y, wb.z, wb.w};
#pragma unroll
      for (int q = 0; q < 8; ++q)
#pragma unroll
        for (int k = 0; k < 8; ++k) acc[q][k] += qv[q] * wv[k];
    }

    // ---- epilogue for class c: w = sigmoid(relu(acc+b1).W2 + b2) ----
    const float* sgc = sg + c * DD;
    float sgv[8];
#pragma unroll
    for (int k = 0; k < 8; ++k) sgv[k] = sgc[jt * 8 + k];

#pragma unroll
    for (int q = 0; q < 8; ++q) {
      float p = 0.f;
#pragma unroll
      for (int k = 0; k < 8; ++k) {
        float h = acc[q][k] + b1v[k];
        h = fmaxf(h, 0.f);
        p += h * w2v[k];
      }
      p += __shfl_xor(p, 1);
      p += __shfl_xor(p, 2);
      p += __shfl_xor(p, 4);
      p += __shfl_xor(p, 8);
      float w = 1.f / (1.f + expf(-(p + b2s)));
      S[q] += w;
#pragma unroll
      for (int k = 0; k < 8; ++k) sgw[q][k] += w * sgv[k];
    }
  }

  // ---- final combine + write ----
#pragma unroll
  for (int q = 0; q < 8; ++q) {
    const int qq = qi * 8 + q;
    float o0[4], o1[4];
#pragma unroll
    for (int k = 0; k < 4; ++k) {
      const int d = jt * 4 + k;  // d in [0,64)
      o0[k] = 0.5f * (qT[2 * d][qq] + qT[2 * d + 1][qq]) * S[q] + qT[d][qq];
      const int e = jt * 8 + 2 * k;  // for d' = 64 + jt*4 + k
      o1[k] = 0.5f * (qT[e][qq] * sgw[q][2 * k] + qT[e + 1][qq] * sgw[q][2 * k + 1]) +
              qT[64 + jt * 4 + k][qq];
    }
    float4 v0 = {o0[0], o0[1], o0[2], o0[3]};
    float4 v1 = {o1[0], o1[1], o1[2], o1[3]};
    *(float4*)(out + (size_t)(qbase + qq) * DD + jt * 4) = v0;
    *(float4*)(out + (size_t)(qbase + qq) * DD + 64 + jt * 4) = v1;
  }
}

// ---------------------------------------------------------------------------
extern "C" void kernel_launch(void* const* d_in, const int* in_sizes, int n_in,
                              void* d_out, int out_size, void* d_ws, size_t ws_size,
                              hipStream_t stream) {
  const float* sfi = (const float*)d_in[0];   // support_feat_inv (1600,128)
  const float* sf  = (const float*)d_in[1];   // support_features (1600,128)
  const float* qf  = (const float*)d_in[2];   // query_features (32768,128)
  const float* W1  = (const float*)d_in[3];   // (257,128)
  const float* b1  = (const float*)d_in[4];   // (128,)
  const float* W2  = (const float*)d_in[5];   // (128,1)
  const float* b2  = (const float*)d_in[6];   // (1,)
  const int* slab  = (const int*)d_in[7];     // support_labels (1600,)
  // d_in[8] = query_labels: unused by reference
  float* out = (float*)d_out;

  float* sg    = (float*)d_ws;        // 16*128
  float* pre_s = sg + CC * DD;        // 16*128
  float* Wt    = pre_s + CC * DD;     // 16*128*128  (~1.02 MB total)

  centers_kernel<<<CC, 512, 0, stream>>>(sfi, sf, slab, sg, pre_s);
  dim3 g2(DD, CC);
  build_wt_kernel<<<g2, HIDN, 0, stream>>>(W1, sg, pre_s, Wt);
  main_kernel<<<QQ / 128, 256, 0, stream>>>(qf, Wt, sg, b1, W2, b2, out);
}

// Round 2
// 106.926 us; speedup vs baseline: 3.0933x; 3.0933x over previous
//
#include <hip/hip_runtime.h>
#include <hip/hip_bf16.h>
#include <stdint.h>

#define DD 128
#define CC 16
#define NS 1600
#define QQ 32768

typedef __attribute__((ext_vector_type(8))) short short8;  // 8 bf16
typedef __attribute__((ext_vector_type(4))) float f32x4;

__device__ inline short f2bf(float x) {
  union { float f; uint32_t u; } v; v.f = x;
  uint32_t r = (v.u + 0x7FFFu + ((v.u >> 16) & 1u)) >> 16;  // RNE
  return (short)r;
}

// ---------------------------------------------------------------------------
// Kernel 1: class centers. grid=16, block=1024 (128 d x 8 slices)
// ---------------------------------------------------------------------------
__global__ __launch_bounds__(1024) void centers_kernel(
    const float* __restrict__ sfi, const float* __restrict__ sf,
    const int* __restrict__ labels, float* __restrict__ sg,
    float* __restrict__ pre_s) {
  const int c = blockIdx.x;
  const int d = threadIdx.x & 127;
  const int s = threadIdx.x >> 7;  // 0..7
  float a = 0.f, b = 0.f, cnt = 0.f;
  const int i0 = s * (NS / 8), i1 = i0 + (NS / 8);
  for (int i = i0; i < i1; ++i) {
    if (labels[i] == c) {
      a += sfi[i * DD + d];
      b += sf[i * DD + d];
      cnt += 1.f;
    }
  }
  __shared__ float A[8][128], B[8][128], CNTs[8];
  A[s][d] = a; B[s][d] = b;
  if (d == 0) CNTs[s] = cnt;
  __syncthreads();
  if (s == 0) {
    a = 0.f; b = 0.f; cnt = 0.f;
#pragma unroll
    for (int k = 0; k < 8; ++k) { a += A[k][d]; b += B[k][d]; cnt += CNTs[k]; }
    cnt = fmaxf(cnt, 1.f);
    float mean = a / cnt;
    sg[c * DD + d] = 1.f / (1.f + expf(-mean));
    pre_s[c * DD + d] = b / cnt;
  }
}

// ---------------------------------------------------------------------------
// Kernel 2: fused per-class weights, TRANSPOSED + bf16 + pre-swizzled.
// Logical WtT[c][j][e] = W1[e][j] + sg[c][e]*W1[128+e][j] + pre_s[c][e]*W1[256][j]
// Stored so that linear global_load_lds staging + XOR-swizzled ds_read works:
// physical 16B unit p (within class) holds row j=p>>4, e-block eb=(p&15)^(j&7).
// grid=16 (c), block=256, 8 iters.
// ---------------------------------------------------------------------------
__global__ __launch_bounds__(256) void build_wt_kernel(
    const float* __restrict__ W1, const float* __restrict__ sg,
    const float* __restrict__ pre_s, short* __restrict__ WtTg) {
  const int c = blockIdx.x, t = threadIdx.x;
  const int eb = (t & 15) ^ ((t >> 4) & 7);
  const int e0 = eb * 8;
  const float* sgc = sg + c * DD;
  const float* prc = pre_s + c * DD;
  for (int it = 0; it < 8; ++it) {
    const int p = it * 256 + t;
    const int j = it * 16 + (t >> 4);
    short8 r;
#pragma unroll
    for (int rr = 0; rr < 8; ++rr) {
      const int e = e0 + rr;
      float v = W1[e * DD + j] + sgc[e] * W1[(DD + e) * DD + j] +
                prc[e] * W1[2 * DD * DD + j];
      r[rr] = f2bf(v);
    }
    *(short8*)(WtTg + (size_t)(c * 2048 + p) * 8) = r;
  }
}

// ---------------------------------------------------------------------------
// Kernel 3: main MFMA kernel. grid=256, block=256 (4 waves, 2x2 over q x j).
// Per block: 128 q. Wave (wq,wj): q in [wq*64,+64), j in [wj*64,+64).
// h^T[j][q] = sum_e WtT[j][e] * q[q][e]  via mfma_f32_16x16x32_bf16
//   A-frag (j rows) from LDS (swizzled), B-frag (q cols) in registers.
// acc init = b1 (folds bias). Fold: p = sum_j relu(h)*W2[j], shfl over l>>4,
// cross-wj combine via p_lds; finisher does sigmoid -> w[q][c], S[q].
// ---------------------------------------------------------------------------
__global__ __launch_bounds__(256, 2) void main_kernel(
    const float* __restrict__ qf, const short* __restrict__ WtTg,
    const float* __restrict__ b1, const float* __restrict__ W2,
    const float* __restrict__ b2, float* __restrict__ w_ws,
    float* __restrict__ S_ws) {
  __shared__ __align__(16) char Wl[2][32768];
  __shared__ float p_lds[2][2][128];

  const int tid = threadIdx.x;
  const int lane = tid & 63;
  const int w = tid >> 6;           // wave 0..3
  const int wq = w >> 1, wj = w & 1;
  const int l15 = lane & 15, l4 = lane >> 4;
  const int qbase = blockIdx.x * 128;

  // ---- B fragments (q^T), 16 frags, f32->bf16 fused ----
  short8 bq[4][4];
#pragma unroll
  for (int qn = 0; qn < 4; ++qn) {
    const float* qrow = qf + (size_t)(qbase + wq * 64 + qn * 16 + l15) * DD;
#pragma unroll
    for (int kb = 0; kb < 4; ++kb) {
      float4 f0 = *(const float4*)(qrow + kb * 32 + l4 * 8);
      float4 f1 = *(const float4*)(qrow + kb * 32 + l4 * 8 + 4);
      short8 r;
      r[0] = f2bf(f0.x); r[1] = f2bf(f0.y); r[2] = f2bf(f0.z); r[3] = f2bf(f0.w);
      r[4] = f2bf(f1.x); r[5] = f2bf(f1.y); r[6] = f2bf(f1.z); r[7] = f2bf(f1.w);
      bq[qn][kb] = r;
    }
  }

  f32x4 b1v[4], w2v[4];
#pragma unroll
  for (int jm = 0; jm < 4; ++jm) {
    b1v[jm] = *(const f32x4*)(b1 + wj * 64 + jm * 16 + l4 * 4);
    w2v[jm] = *(const f32x4*)(W2 + wj * 64 + jm * 16 + l4 * 4);
  }
  const float b2s = b2[0];

  const char* gsrc = (const char*)WtTg;
  const int soff = w * 1024 + lane * 16;  // per-thread staging offset

  // ---- prologue: stage class 0 into buf 0 ----
#pragma unroll
  for (int i = 0; i < 8; ++i) {
    const int off = i * 4096 + soff;
    __builtin_amdgcn_global_load_lds(
        (const __attribute__((address_space(1))) uint32_t*)(gsrc + off),
        (__attribute__((address_space(3))) uint32_t*)(&Wl[0][0] + off), 16, 0, 0);
  }
  asm volatile("s_waitcnt vmcnt(0)" ::: "memory");
  __syncthreads();

  float S = 0.f;

  for (int c = 0; c < CC; ++c) {
    const int buf = c & 1;
    if (c < CC - 1) {  // prefetch next class (async, drains at the barrier)
      const char* gc = gsrc + (size_t)(c + 1) * 32768;
#pragma unroll
      for (int i = 0; i < 8; ++i) {
        const int off = i * 4096 + soff;
        __builtin_amdgcn_global_load_lds(
            (const __attribute__((address_space(1))) uint32_t*)(gc + off),
            (__attribute__((address_space(3))) uint32_t*)(&Wl[buf ^ 1][0] + off),
            16, 0, 0);
      }
    }

    f32x4 acc[4][4];
#pragma unroll
    for (int jm = 0; jm < 4; ++jm)
#pragma unroll
      for (int qn = 0; qn < 4; ++qn) acc[jm][qn] = b1v[jm];

    const char* wb = &Wl[buf][0];
#pragma unroll
    for (int jm = 0; jm < 4; ++jm) {
      const int rowb = (wj * 64 + jm * 16 + l15) * 256;
#pragma unroll
      for (int kb = 0; kb < 4; ++kb) {
        const int byte = rowb + (((kb * 4 + l4) ^ (l15 & 7)) << 4);
        short8 af = *(const short8*)(wb + byte);
#pragma unroll
        for (int qn = 0; qn < 4; ++qn)
          acc[jm][qn] = __builtin_amdgcn_mfma_f32_16x16x32_bf16(
              af, bq[qn][kb], acc[jm][qn], 0, 0, 0);
      }
    }

    // ---- fold: p[q] partial over this wave's 64 j ----
    float pv[4];
#pragma unroll
    for (int qn = 0; qn < 4; ++qn) {
      float p = 0.f;
#pragma unroll
      for (int jm = 0; jm < 4; ++jm)
#pragma unroll
        for (int i = 0; i < 4; ++i)
          p += fmaxf(acc[jm][qn][i], 0.f) * w2v[jm][i];
      p += __shfl_xor(p, 16);
      p += __shfl_xor(p, 32);
      pv[qn] = p;
    }
    if (lane < 16) {
#pragma unroll
      for (int qn = 0; qn < 4; ++qn)
        p_lds[buf][wj][wq * 64 + qn * 16 + l15] = pv[qn];
    }
    __syncthreads();  // p_lds ready; also drains prefetch vmcnt before next read

    if (tid < 128) {
      const float pf = p_lds[buf][0][tid] + p_lds[buf][1][tid] + b2s;
      const float wgt = 1.f / (1.f + __expf(-pf));
      S += wgt;
      w_ws[(size_t)(qbase + tid) * 16 + c] = wgt;
    }
  }
  if (tid < 128) S_ws[qbase + tid] = S;
}

// ---------------------------------------------------------------------------
// Kernel 4: epilogue. grid=512, block=256 (8 q-slots x 32 e-chunks), 8 q-iters.
// sgw[e] = sum_c w[q][c]*sg[c][e] with sg chunk register-resident.
// out[d<64]  = 0.5*(qf[2d]+qf[2d+1])*S + qf[d]
// out[d>=64] = 0.5*(qf[e]*sgw[e]+qf[e+1]*sgw[e+1]) + qf[d], e=2(d-64)
// ---------------------------------------------------------------------------
__global__ __launch_bounds__(256) void agg_kernel(
    const float* __restrict__ qf, const float* __restrict__ sg,
    const float* __restrict__ w_ws, const float* __restrict__ S_ws,
    float* __restrict__ out) {
  const int t = threadIdx.x;
  const int s = t >> 5;        // 0..7 q-slot
  const int ec = t & 31;       // e-chunk: e0 = ec*4
  const int e0 = ec * 4;
  const int qbase = blockIdx.x * 64;

  float4 sgv[16];
#pragma unroll
  for (int c = 0; c < 16; ++c) sgv[c] = *(const float4*)(sg + c * DD + e0);

  for (int qi = 0; qi < 8; ++qi) {
    const int q = qbase + qi * 8 + s;
    const float* wr = w_ws + (size_t)q * 16;
    float4 w0 = *(const float4*)(wr);
    float4 w1 = *(const float4*)(wr + 4);
    float4 w2 = *(const float4*)(wr + 8);
    float4 w3 = *(const float4*)(wr + 12);
    const float Sv = S_ws[q];

    f32x4 sgw = {0.f, 0.f, 0.f, 0.f};
    const float wc[16] = {w0.x, w0.y, w0.z, w0.w, w1.x, w1.y, w1.z, w1.w,
                          w2.x, w2.y, w2.z, w2.w, w3.x, w3.y, w3.z, w3.w};
#pragma unroll
    for (int c = 0; c < 16; ++c) {
      sgw.x += wc[c] * sgv[c].x;
      sgw.y += wc[c] * sgv[c].y;
      sgw.z += wc[c] * sgv[c].z;
      sgw.w += wc[c] * sgv[c].w;
    }

    const float* qrow = qf + (size_t)q * DD;
    float4 qa = *(const float4*)(qrow + e0);
    float2 qd = *(const float2*)(qrow + 2 * ec);
    float2 qu = *(const float2*)(qrow + 64 + 2 * ec);

    float2 lo, hi;
    lo.x = 0.5f * (qa.x + qa.y) * Sv + qd.x;
    lo.y = 0.5f * (qa.z + qa.w) * Sv + qd.y;
    hi.x = 0.5f * (qa.x * sgw.x + qa.y * sgw.y) + qu.x;
    hi.y = 0.5f * (qa.z * sgw.z + qa.w * sgw.w) + qu.y;

    float* orow = out + (size_t)q * DD;
    *(float2*)(orow + 2 * ec) = lo;
    *(float2*)(orow + 64 + 2 * ec) = hi;
  }
}

// ---------------------------------------------------------------------------
extern "C" void kernel_launch(void* const* d_in, const int* in_sizes, int n_in,
                              void* d_out, int out_size, void* d_ws, size_t ws_size,
                              hipStream_t stream) {
  const float* sfi = (const float*)d_in[0];
  const float* sf  = (const float*)d_in[1];
  const float* qf  = (const float*)d_in[2];
  const float* W1  = (const float*)d_in[3];
  const float* b1  = (const float*)d_in[4];
  const float* W2  = (const float*)d_in[5];
  const float* b2  = (const float*)d_in[6];
  const int* slab  = (const int*)d_in[7];
  float* out = (float*)d_out;

  float* sg    = (float*)d_ws;                 // 2048 f
  float* pre_s = sg + CC * DD;                 // 2048 f
  float* S_ws  = pre_s + CC * DD;              // 32768 f
  float* w_ws  = S_ws + QQ;                    // 524288 f
  short* WtTg  = (short*)(w_ws + (size_t)QQ * CC);  // 16*2048*8 shorts (512 KB)

  centers_kernel<<<CC, 1024, 0, stream>>>(sfi, sf, slab, sg, pre_s);
  build_wt_kernel<<<CC, 256, 0, stream>>>(W1, sg, pre_s, WtTg);
  main_kernel<<<QQ / 128, 256, 0, stream>>>(qf, WtTg, b1, W2, b2, w_ws, S_ws);
  agg_kernel<<<QQ / 64, 256, 0, stream>>>(qf, sg, w_ws, S_ws, out);
}

// Round 3
// 81.237 us; speedup vs baseline: 4.0714x; 1.3162x over previous
//
#include <hip/hip_runtime.h>
#include <hip/hip_bf16.h>
#include <stdint.h>

#define DD 128
#define CC 16
#define NS 1600
#define QQ 32768
#define NBLK 64  // centers partial blocks (NS/NBLK = 25 rows each)

typedef __attribute__((ext_vector_type(8))) short short8;  // 8 bf16
typedef __attribute__((ext_vector_type(4))) float f32x4;

__device__ inline short f2bf(float x) {
  union { float f; uint32_t u; } v; v.f = x;
  uint32_t r = (v.u + 0x7FFFu + ((v.u >> 16) & 1u)) >> 16;  // RNE
  return (short)r;
}

// ---------------------------------------------------------------------------
// Kernel 1: per-block partial class sums. grid=64, block=256.
// Halves (t>>7) process alternating rows -> no LDS RMW race; label is
// wave-uniform so acc[s][lbl][d] writes are conflict-free (d = lane id).
// Deterministic: partials summed in fixed order by build_wt (no FP atomics).
// ---------------------------------------------------------------------------
__global__ __launch_bounds__(256) void centers_partial(
    const float* __restrict__ sfi, const float* __restrict__ sf,
    const int* __restrict__ labels, float* __restrict__ partA,
    float* __restrict__ partB, float* __restrict__ pcnt) {
  __shared__ float accA[2][CC][DD];
  __shared__ float accB[2][CC][DD];
  __shared__ float cnt[2][CC];
  const int t = threadIdx.x;
  const int d = t & 127, s = t >> 7;
  for (int i = t; i < 2 * CC * DD; i += 256) {
    ((float*)accA)[i] = 0.f;
    ((float*)accB)[i] = 0.f;
  }
  if (t < 2 * CC) ((float*)cnt)[t] = 0.f;
  __syncthreads();

  const int base = blockIdx.x * (NS / NBLK);
  for (int i = s; i < NS / NBLK; i += 2) {
    const int r = base + i;
    const int lbl = labels[r];
    accA[s][lbl][d] += sfi[(size_t)r * DD + d];
    accB[s][lbl][d] += sf[(size_t)r * DD + d];
    if (d == 0) cnt[s][lbl] += 1.f;
  }
  __syncthreads();

  float* pa = partA + (size_t)blockIdx.x * (CC * DD);
  float* pb = partB + (size_t)blockIdx.x * (CC * DD);
  for (int i = t; i < CC * DD; i += 256) {
    pa[i] = ((float*)accA)[i] + ((float*)accA)[CC * DD + i];
    pb[i] = ((float*)accB)[i] + ((float*)accB)[CC * DD + i];
  }
  if (t < CC) pcnt[blockIdx.x * CC + t] = cnt[0][t] + cnt[1][t];
}

// ---------------------------------------------------------------------------
// Kernel 2: finalize centers + fused per-class weights (bf16, transposed,
// pre-swizzled). Layout UNCHANGED from round 2 (main_kernel depends on it):
// physical 16B unit p holds row j=p>>4, e-block eb=(p&15)^(j&7).
// grid=16 (c), block=256.
// ---------------------------------------------------------------------------
__global__ __launch_bounds__(256) void build_wt_kernel(
    const float* __restrict__ W1, const float* __restrict__ partA,
    const float* __restrict__ partB, const float* __restrict__ pcnt,
    float* __restrict__ sg_out, short* __restrict__ WtTg) {
  __shared__ float sgc[DD], prc[DD];
  const int c = blockIdx.x, t = threadIdx.x;

  float cnt = 0.f;
  for (int b = 0; b < NBLK; ++b) cnt += pcnt[b * CC + c];
  cnt = fmaxf(cnt, 1.f);
  if (t < 128) {
    float a = 0.f;
    for (int b = 0; b < NBLK; ++b) a += partA[(size_t)b * (CC * DD) + c * DD + t];
    const float m = a / cnt;
    const float s = 1.f / (1.f + expf(-m));
    sgc[t] = s;
    sg_out[c * DD + t] = s;
  } else {
    const int d = t - 128;
    float a = 0.f;
    for (int b = 0; b < NBLK; ++b) a += partB[(size_t)b * (CC * DD) + c * DD + d];
    prc[d] = a / cnt;
  }
  __syncthreads();

  const int eb = (t & 15) ^ ((t >> 4) & 7);
  const int e0 = eb * 8;
  for (int it = 0; it < 8; ++it) {
    const int p = it * 256 + t;
    const int j = it * 16 + (t >> 4);
    short8 r;
#pragma unroll
    for (int rr = 0; rr < 8; ++rr) {
      const int e = e0 + rr;
      float v = W1[e * DD + j] + sgc[e] * W1[(DD + e) * DD + j] +
                prc[e] * W1[2 * DD * DD + j];
      r[rr] = f2bf(v);
    }
    *(short8*)(WtTg + (size_t)(c * 2048 + p) * 8) = r;
  }
}

// ---------------------------------------------------------------------------
// Kernel 3: main MFMA kernel. grid=256, block=256 (4 waves, 2x2 over q x j).
// h^T[j][q] = sum_e WtT[j][e]*q[q][e] via mfma_f32_16x16x32_bf16; acc init=b1.
// Fold p = sum_j relu(h)*W2[j] (lane-local + 2 shfl), sigmoid -> w_ws, S_ws.
// ---------------------------------------------------------------------------
__global__ __launch_bounds__(256, 2) void main_kernel(
    const float* __restrict__ qf, const short* __restrict__ WtTg,
    const float* __restrict__ b1, const float* __restrict__ W2,
    const float* __restrict__ b2, float* __restrict__ w_ws,
    float* __restrict__ S_ws) {
  __shared__ __align__(16) char Wl[2][32768];
  __shared__ float p_lds[2][2][128];

  const int tid = threadIdx.x;
  const int lane = tid & 63;
  const int w = tid >> 6;           // wave 0..3
  const int wq = w >> 1, wj = w & 1;
  const int l15 = lane & 15, l4 = lane >> 4;
  const int qbase = blockIdx.x * 128;

  // ---- B fragments (q^T), f32->bf16 fused ----
  short8 bq[4][4];
#pragma unroll
  for (int qn = 0; qn < 4; ++qn) {
    const float* qrow = qf + (size_t)(qbase + wq * 64 + qn * 16 + l15) * DD;
#pragma unroll
    for (int kb = 0; kb < 4; ++kb) {
      float4 f0 = *(const float4*)(qrow + kb * 32 + l4 * 8);
      float4 f1 = *(const float4*)(qrow + kb * 32 + l4 * 8 + 4);
      short8 r;
      r[0] = f2bf(f0.x); r[1] = f2bf(f0.y); r[2] = f2bf(f0.z); r[3] = f2bf(f0.w);
      r[4] = f2bf(f1.x); r[5] = f2bf(f1.y); r[6] = f2bf(f1.z); r[7] = f2bf(f1.w);
      bq[qn][kb] = r;
    }
  }

  f32x4 b1v[4], w2v[4];
#pragma unroll
  for (int jm = 0; jm < 4; ++jm) {
    b1v[jm] = *(const f32x4*)(b1 + wj * 64 + jm * 16 + l4 * 4);
    w2v[jm] = *(const f32x4*)(W2 + wj * 64 + jm * 16 + l4 * 4);
  }
  const float b2s = b2[0];

  const char* gsrc = (const char*)WtTg;
  const int soff = w * 1024 + lane * 16;

  // ---- prologue: stage class 0 into buf 0 ----
#pragma unroll
  for (int i = 0; i < 8; ++i) {
    const int off = i * 4096 + soff;
    __builtin_amdgcn_global_load_lds(
        (const __attribute__((address_space(1))) uint32_t*)(gsrc + off),
        (__attribute__((address_space(3))) uint32_t*)(&Wl[0][0] + off), 16, 0, 0);
  }
  asm volatile("s_waitcnt vmcnt(0)" ::: "memory");
  __syncthreads();

  float S = 0.f;

  for (int c = 0; c < CC; ++c) {
    const int buf = c & 1;
    if (c < CC - 1) {  // async prefetch next class, drains at the barrier
      const char* gc = gsrc + (size_t)(c + 1) * 32768;
#pragma unroll
      for (int i = 0; i < 8; ++i) {
        const int off = i * 4096 + soff;
        __builtin_amdgcn_global_load_lds(
            (const __attribute__((address_space(1))) uint32_t*)(gc + off),
            (__attribute__((address_space(3))) uint32_t*)(&Wl[buf ^ 1][0] + off),
            16, 0, 0);
      }
    }

    f32x4 acc[4][4];
#pragma unroll
    for (int jm = 0; jm < 4; ++jm)
#pragma unroll
      for (int qn = 0; qn < 4; ++qn) acc[jm][qn] = b1v[jm];

    const char* wb = &Wl[buf][0];
#pragma unroll
    for (int jm = 0; jm < 4; ++jm) {
      const int rowb = (wj * 64 + jm * 16 + l15) * 256;
#pragma unroll
      for (int kb = 0; kb < 4; ++kb) {
        const int byte = rowb + (((kb * 4 + l4) ^ (l15 & 7)) << 4);
        short8 af = *(const short8*)(wb + byte);
#pragma unroll
        for (int qn = 0; qn < 4; ++qn)
          acc[jm][qn] = __builtin_amdgcn_mfma_f32_16x16x32_bf16(
              af, bq[qn][kb], acc[jm][qn], 0, 0, 0);
      }
    }

    float pv[4];
#pragma unroll
    for (int qn = 0; qn < 4; ++qn) {
      float p = 0.f;
#pragma unroll
      for (int jm = 0; jm < 4; ++jm)
#pragma unroll
        for (int i = 0; i < 4; ++i)
          p += fmaxf(acc[jm][qn][i], 0.f) * w2v[jm][i];
      p += __shfl_xor(p, 16);
      p += __shfl_xor(p, 32);
      pv[qn] = p;
    }
    if (lane < 16) {
#pragma unroll
      for (int qn = 0; qn < 4; ++qn)
        p_lds[buf][wj][wq * 64 + qn * 16 + l15] = pv[qn];
    }
    __syncthreads();  // p_lds ready; also drains prefetch before buffer reuse

    if (tid < 128) {
      const float pf = p_lds[buf][0][tid] + p_lds[buf][1][tid] + b2s;
      const float wgt = 1.f / (1.f + __expf(-pf));
      S += wgt;
      w_ws[(size_t)(qbase + tid) * 16 + c] = wgt;
    }
  }
  if (tid < 128) S_ws[qbase + tid] = S;
}

// ---------------------------------------------------------------------------
// Kernel 4: epilogue (unchanged). grid=512, block=256.
// ---------------------------------------------------------------------------
__global__ __launch_bounds__(256) void agg_kernel(
    const float* __restrict__ qf, const float* __restrict__ sg,
    const float* __restrict__ w_ws, const float* __restrict__ S_ws,
    float* __restrict__ out) {
  const int t = threadIdx.x;
  const int s = t >> 5;
  const int ec = t & 31;
  const int e0 = ec * 4;
  const int qbase = blockIdx.x * 64;

  float4 sgv[16];
#pragma unroll
  for (int c = 0; c < 16; ++c) sgv[c] = *(const float4*)(sg + c * DD + e0);

  for (int qi = 0; qi < 8; ++qi) {
    const int q = qbase + qi * 8 + s;
    const float* wr = w_ws + (size_t)q * 16;
    float4 w0 = *(const float4*)(wr);
    float4 w1 = *(const float4*)(wr + 4);
    float4 w2 = *(const float4*)(wr + 8);
    float4 w3 = *(const float4*)(wr + 12);
    const float Sv = S_ws[q];

    f32x4 sgw = {0.f, 0.f, 0.f, 0.f};
    const float wc[16] = {w0.x, w0.y, w0.z, w0.w, w1.x, w1.y, w1.z, w1.w,
                          w2.x, w2.y, w2.z, w2.w, w3.x, w3.y, w3.z, w3.w};
#pragma unroll
    for (int c = 0; c < 16; ++c) {
      sgw.x += wc[c] * sgv[c].x;
      sgw.y += wc[c] * sgv[c].y;
      sgw.z += wc[c] * sgv[c].z;
      sgw.w += wc[c] * sgv[c].w;
    }

    const float* qrow = qf + (size_t)q * DD;
    float4 qa = *(const float4*)(qrow + e0);
    float2 qd = *(const float2*)(qrow + 2 * ec);
    float2 qu = *(const float2*)(qrow + 64 + 2 * ec);

    float2 lo, hi;
    lo.x = 0.5f * (qa.x + qa.y) * Sv + qd.x;
    lo.y = 0.5f * (qa.z + qa.w) * Sv + qd.y;
    hi.x = 0.5f * (qa.x * sgw.x + qa.y * sgw.y) + qu.x;
    hi.y = 0.5f * (qa.z * sgw.z + qa.w * sgw.w) + qu.y;

    float* orow = out + (size_t)q * DD;
    *(float2*)(orow + 2 * ec) = lo;
    *(float2*)(orow + 64 + 2 * ec) = hi;
  }
}

// ---------------------------------------------------------------------------
extern "C" void kernel_launch(void* const* d_in, const int* in_sizes, int n_in,
                              void* d_out, int out_size, void* d_ws, size_t ws_size,
                              hipStream_t stream) {
  const float* sfi = (const float*)d_in[0];
  const float* sf  = (const float*)d_in[1];
  const float* qf  = (const float*)d_in[2];
  const float* W1  = (const float*)d_in[3];
  const float* b1  = (const float*)d_in[4];
  const float* W2  = (const float*)d_in[5];
  const float* b2  = (const float*)d_in[6];
  const int* slab  = (const int*)d_in[7];
  float* out = (float*)d_out;

  float* sg    = (float*)d_ws;                       // 2048
  float* S_ws  = sg + CC * DD;                       // 32768
  float* w_ws  = S_ws + QQ;                          // 524288
  short* WtTg  = (short*)(w_ws + (size_t)QQ * CC);   // 262144 shorts (512 KB)
  float* partA = (float*)(WtTg + CC * DD * DD);      // 64*2048
  float* partB = partA + NBLK * CC * DD;             // 64*2048
  float* pcnt  = partB + NBLK * CC * DD;             // 64*16

  centers_partial<<<NBLK, 256, 0, stream>>>(sfi, sf, slab, partA, partB, pcnt);
  build_wt_kernel<<<CC, 256, 0, stream>>>(W1, partA, partB, pcnt, sg, WtTg);
  main_kernel<<<QQ / 128, 256, 0, stream>>>(qf, WtTg, b1, W2, b2, w_ws, S_ws);
  agg_kernel<<<QQ / 64, 256, 0, stream>>>(qf, sg, w_ws, S_ws, out);
}

// Round 4
// 65.924 us; speedup vs baseline: 5.0171x; 1.2323x over previous
//
#include <hip/hip_runtime.h>
#include <hip/hip_bf16.h>
#include <stdint.h>

#define DD 128
#define CC 16
#define NS 1600
#define QQ 32768
#define NBLK 64

typedef __attribute__((ext_vector_type(8))) short short8;  // 8 bf16
typedef __attribute__((ext_vector_type(4))) float f32x4;

__device__ inline short f2bf(float x) {
  union { float f; uint32_t u; } v; v.f = x;
  uint32_t r = (v.u + 0x7FFFu + ((v.u >> 16) & 1u)) >> 16;  // RNE
  return (short)r;
}

__device__ inline uint32_t pk2bf(float lo, float hi) {
  __hip_bfloat162 h = __float22bfloat162_rn(make_float2(lo, hi));  // RNE, lo->low16
  union { __hip_bfloat162 h2; uint32_t u; } v; v.h2 = h;
  return v.u;
}

// ---------------------------------------------------------------------------
// Kernel 1: per-block partial class sums. grid=64, block=256. (unchanged)
// ---------------------------------------------------------------------------
__global__ __launch_bounds__(256) void centers_partial(
    const float* __restrict__ sfi, const float* __restrict__ sf,
    const int* __restrict__ labels, float* __restrict__ partA,
    float* __restrict__ partB, float* __restrict__ pcnt) {
  __shared__ float accA[2][CC][DD];
  __shared__ float accB[2][CC][DD];
  __shared__ float cnt[2][CC];
  const int t = threadIdx.x;
  const int d = t & 127, s = t >> 7;
  for (int i = t; i < 2 * CC * DD; i += 256) {
    ((float*)accA)[i] = 0.f;
    ((float*)accB)[i] = 0.f;
  }
  if (t < 2 * CC) ((float*)cnt)[t] = 0.f;
  __syncthreads();

  const int base = blockIdx.x * (NS / NBLK);
  for (int i = s; i < NS / NBLK; i += 2) {
    const int r = base + i;
    const int lbl = labels[r];
    accA[s][lbl][d] += sfi[(size_t)r * DD + d];
    accB[s][lbl][d] += sf[(size_t)r * DD + d];
    if (d == 0) cnt[s][lbl] += 1.f;
  }
  __syncthreads();

  float* pa = partA + (size_t)blockIdx.x * (CC * DD);
  float* pb = partB + (size_t)blockIdx.x * (CC * DD);
  for (int i = t; i < CC * DD; i += 256) {
    pa[i] = ((float*)accA)[i] + ((float*)accA)[CC * DD + i];
    pb[i] = ((float*)accB)[i] + ((float*)accB)[CC * DD + i];
  }
  if (t < CC) pcnt[blockIdx.x * CC + t] = cnt[0][t] + cnt[1][t];
}

// ---------------------------------------------------------------------------
// Kernel 2: finalize centers + fused per-class weights in FRAGMENT order.
// 16B unit u within class c: u = w*256 + kb*64 + lane  (w=0..7, kb=0..3)
//   holds WtT[j][e0..e0+7] bf16, j = w*16 + (lane&15), e0 = kb*32 + (lane>>4)*8
// so main's wave-w A-frag load (cls,kb) is ONE coalesced 1KB global_load.
// grid=16 (c), block=256.
// ---------------------------------------------------------------------------
__global__ __launch_bounds__(256) void build_wt_kernel(
    const float* __restrict__ W1, const float* __restrict__ partA,
    const float* __restrict__ partB, const float* __restrict__ pcnt,
    float* __restrict__ sg_out, short* __restrict__ WtTg) {
  __shared__ float sgc[DD], prc[DD];
  const int c = blockIdx.x, t = threadIdx.x;

  float cnt = 0.f;
  for (int b = 0; b < NBLK; ++b) cnt += pcnt[b * CC + c];
  cnt = fmaxf(cnt, 1.f);
  if (t < 128) {
    float a = 0.f;
    for (int b = 0; b < NBLK; ++b) a += partA[(size_t)b * (CC * DD) + c * DD + t];
    const float m = a / cnt;
    const float s = 1.f / (1.f + expf(-m));
    sgc[t] = s;
    sg_out[c * DD + t] = s;
  } else {
    const int d = t - 128;
    float a = 0.f;
    for (int b = 0; b < NBLK; ++b) a += partB[(size_t)b * (CC * DD) + c * DD + d];
    prc[d] = a / cnt;
  }
  __syncthreads();

  for (int it = 0; it < 8; ++it) {
    const int u = it * 256 + t;        // 0..2047
    const int w_ = u >> 8;             // 0..7
    const int kb = (u >> 6) & 3;
    const int lane = u & 63;
    const int j = w_ * 16 + (lane & 15);
    const int e0 = kb * 32 + (lane >> 4) * 8;
    short8 r;
#pragma unroll
    for (int rr = 0; rr < 8; ++rr) {
      const int e = e0 + rr;
      float v = W1[e * DD + j] + sgc[e] * W1[(DD + e) * DD + j] +
                prc[e] * W1[2 * DD * DD + j];
      r[rr] = f2bf(v);
    }
    *(short8*)(WtTg + ((size_t)c * 2048 + u) * 8) = r;
  }
}

// ---------------------------------------------------------------------------
// Kernel 3: main MFMA kernel, barrier-free class loop.
// grid=256, block=512 (8 waves). Block: 128 q. Wave w: j rows [w*16, w*16+16),
// all 128 q. W frags direct global->VGPR (L2-resident, coalesced 1KB loads),
// register-double-buffered across classes. Per class: 4 loads + 32 MFMA +
// lane-local relu/W2 fold + 2 shfl -> p_part[w][c][q]. ONE barrier, then
// epilogue: w[q][c] = sigmoid(sum_w p_part + b2), written as f32x4 [q][16].
// ---------------------------------------------------------------------------
__global__ __launch_bounds__(512, 2) void main_kernel(
    const float* __restrict__ qf, const short* __restrict__ WtTg,
    const float* __restrict__ b1, const float* __restrict__ W2,
    const float* __restrict__ b2, float* __restrict__ w_ws) {
  __shared__ float p_part[8][CC][128];  // 64 KiB

  const int tid = threadIdx.x;
  const int lane = tid & 63;
  const int w = tid >> 6;  // 0..7
  const int l15 = lane & 15, l4 = lane >> 4;
  const int qbase = blockIdx.x * 128;

  // ---- B fragments: 128 q x 128 e, packed f32->bf16 ----
  short8 bq[8][4];
#pragma unroll
  for (int qn = 0; qn < 8; ++qn) {
    const float* qrow = qf + (size_t)(qbase + qn * 16 + l15) * DD;
#pragma unroll
    for (int kb = 0; kb < 4; ++kb) {
      const float* p0 = qrow + kb * 32 + l4 * 8;
      f32x4 f0 = *(const f32x4*)(p0);
      f32x4 f1 = *(const f32x4*)(p0 + 4);
      union { short8 s; uint32_t u[4]; } r;
      r.u[0] = pk2bf(f0[0], f0[1]);
      r.u[1] = pk2bf(f0[2], f0[3]);
      r.u[2] = pk2bf(f1[0], f1[1]);
      r.u[3] = pk2bf(f1[2], f1[3]);
      bq[qn][kb] = r.s;
    }
  }

  const f32x4 b1v = *(const f32x4*)(b1 + w * 16 + l4 * 4);
  const f32x4 w2v = *(const f32x4*)(W2 + w * 16 + l4 * 4);
  const float b2s = b2[0];

  const char* wbase = (const char*)WtTg + w * 4096 + lane * 16;

#define LOADW(dst, cls)                                                     \
  {                                                                         \
    _Pragma("unroll") for (int kb = 0; kb < 4; ++kb) dst[kb] =              \
        *(const short8*)(wbase + (size_t)(cls)*32768 + kb * 1024);          \
  }

#define COMPUTE(wf, cls)                                                    \
  {                                                                         \
    f32x4 acc[8];                                                           \
    _Pragma("unroll") for (int qn = 0; qn < 8; ++qn) acc[qn] = b1v;         \
    _Pragma("unroll") for (int kb = 0; kb < 4; ++kb)                        \
        _Pragma("unroll") for (int qn = 0; qn < 8; ++qn) acc[qn] =          \
            __builtin_amdgcn_mfma_f32_16x16x32_bf16(wf[kb], bq[qn][kb],     \
                                                    acc[qn], 0, 0, 0);      \
    _Pragma("unroll") for (int qn = 0; qn < 8; ++qn) {                      \
      float p = 0.f;                                                        \
      _Pragma("unroll") for (int i = 0; i < 4; ++i)                         \
          p += fmaxf(acc[qn][i], 0.f) * w2v[i];                             \
      p += __shfl_xor(p, 16);                                               \
      p += __shfl_xor(p, 32);                                               \
      if (l4 == 0) p_part[w][cls][qn * 16 + l15] = p;                       \
    }                                                                       \
  }

  short8 wfA[4], wfB[4];
  LOADW(wfA, 0);
  for (int c = 0; c < CC; c += 2) {
    LOADW(wfB, c + 1);
    COMPUTE(wfA, c);
    if (c + 2 < CC) LOADW(wfA, c + 2);
    COMPUTE(wfB, c + 1);
  }
#undef LOADW
#undef COMPUTE

  __syncthreads();

  // ---- epilogue: thread (q = tid&127, cg = tid>>7) -> 4 classes ----
  {
    const int q = tid & 127;
    const int cg = tid >> 7;  // 0..3
    float pv[4];
#pragma unroll
    for (int k = 0; k < 4; ++k) {
      const int c = cg * 4 + k;
      float s = 0.f;
#pragma unroll
      for (int wv = 0; wv < 8; ++wv) s += p_part[wv][c][q];
      pv[k] = 1.f / (1.f + __expf(-(s + b2s)));
    }
    f32x4 o = {pv[0], pv[1], pv[2], pv[3]};
    *(f32x4*)(w_ws + ((size_t)(qbase + q)) * 16 + cg * 4) = o;
  }
}

// ---------------------------------------------------------------------------
// Kernel 4: epilogue. grid=512, block=256. S computed locally from w row.
// out[d<64]  = 0.5*(qf[2d]+qf[2d+1])*S + qf[d]
// out[d>=64] = 0.5*(qf[e]*sgw[e]+qf[e+1]*sgw[e+1]) + qf[d], e=2(d-64)
// ---------------------------------------------------------------------------
__global__ __launch_bounds__(256) void agg_kernel(
    const float* __restrict__ qf, const float* __restrict__ sg,
    const float* __restrict__ w_ws, float* __restrict__ out) {
  const int t = threadIdx.x;
  const int s = t >> 5;
  const int ec = t & 31;
  const int e0 = ec * 4;
  const int qbase = blockIdx.x * 64;

  float4 sgv[16];
#pragma unroll
  for (int c = 0; c < 16; ++c) sgv[c] = *(const float4*)(sg + c * DD + e0);

  for (int qi = 0; qi < 8; ++qi) {
    const int q = qbase + qi * 8 + s;
    const float* wr = w_ws + (size_t)q * 16;
    float4 w0 = *(const float4*)(wr);
    float4 w1 = *(const float4*)(wr + 4);
    float4 w2 = *(const float4*)(wr + 8);
    float4 w3 = *(const float4*)(wr + 12);
    const float wc[16] = {w0.x, w0.y, w0.z, w0.w, w1.x, w1.y, w1.z, w1.w,
                          w2.x, w2.y, w2.z, w2.w, w3.x, w3.y, w3.z, w3.w};
    float Sv = 0.f;
#pragma unroll
    for (int c = 0; c < 16; ++c) Sv += wc[c];

    f32x4 sgw = {0.f, 0.f, 0.f, 0.f};
#pragma unroll
    for (int c = 0; c < 16; ++c) {
      sgw.x += wc[c] * sgv[c].x;
      sgw.y += wc[c] * sgv[c].y;
      sgw.z += wc[c] * sgv[c].z;
      sgw.w += wc[c] * sgv[c].w;
    }

    const float* qrow = qf + (size_t)q * DD;
    float4 qa = *(const float4*)(qrow + e0);
    float2 qd = *(const float2*)(qrow + 2 * ec);
    float2 qu = *(const float2*)(qrow + 64 + 2 * ec);

    float2 lo, hi;
    lo.x = 0.5f * (qa.x + qa.y) * Sv + qd.x;
    lo.y = 0.5f * (qa.z + qa.w) * Sv + qd.y;
    hi.x = 0.5f * (qa.x * sgw.x + qa.y * sgw.y) + qu.x;
    hi.y = 0.5f * (qa.z * sgw.z + qa.w * sgw.w) + qu.y;

    float* orow = out + (size_t)q * DD;
    *(float2*)(orow + 2 * ec) = lo;
    *(float2*)(orow + 64 + 2 * ec) = hi;
  }
}

// ---------------------------------------------------------------------------
extern "C" void kernel_launch(void* const* d_in, const int* in_sizes, int n_in,
                              void* d_out, int out_size, void* d_ws, size_t ws_size,
                              hipStream_t stream) {
  const float* sfi = (const float*)d_in[0];
  const float* sf  = (const float*)d_in[1];
  const float* qf  = (const float*)d_in[2];
  const float* W1  = (const float*)d_in[3];
  const float* b1  = (const float*)d_in[4];
  const float* W2  = (const float*)d_in[5];
  const float* b2  = (const float*)d_in[6];
  const int* slab  = (const int*)d_in[7];
  float* out = (float*)d_out;

  float* sg    = (float*)d_ws;                       // 2048 f
  float* w_ws  = sg + CC * DD;                       // 524288 f  [q][16]
  short* WtTg  = (short*)(w_ws + (size_t)QQ * CC);   // 262144 shorts (512 KB)
  float* partA = (float*)(WtTg + CC * DD * DD);      // 64*2048 f
  float* partB = partA + NBLK * CC * DD;             // 64*2048 f
  float* pcnt  = partB + NBLK * CC * DD;             // 64*16 f

  centers_partial<<<NBLK, 256, 0, stream>>>(sfi, sf, slab, partA, partB, pcnt);
  build_wt_kernel<<<CC, 256, 0, stream>>>(W1, partA, partB, pcnt, sg, WtTg);
  main_kernel<<<QQ / 128, 512, 0, stream>>>(qf, WtTg, b1, W2, b2, w_ws);
  agg_kernel<<<QQ / 64, 256, 0, stream>>>(qf, sg, w_ws, out);
}

// Round 5
// 57.218 us; speedup vs baseline: 5.7806x; 1.1522x over previous
//
#include <hip/hip_runtime.h>
#include <hip/hip_bf16.h>
#include <stdint.h>

#define DD 128
#define CC 16
#define NS 1600
#define QQ 32768
#define NBLK 64

typedef __attribute__((ext_vector_type(8))) short short8;   // 8 bf16
typedef __attribute__((ext_vector_type(4))) short short4v;  // 4 bf16
typedef __attribute__((ext_vector_type(4))) float f32x4;

__device__ inline short f2bf(float x) {
  union { float f; uint32_t u; } v; v.f = x;
  uint32_t r = (v.u + 0x7FFFu + ((v.u >> 16) & 1u)) >> 16;  // RNE
  return (short)r;
}

__device__ inline uint32_t pk2bf(float lo, float hi) {
  __hip_bfloat162 h = __float22bfloat162_rn(make_float2(lo, hi));  // lo->low16
  union { __hip_bfloat162 h2; uint32_t u; } v; v.h2 = h;
  return v.u;
}

// ---------------------------------------------------------------------------
// Kernel 1: fused prep. grid=320, block=256.
//  blocks [0,64):  per-block partial class sums (unchanged math).
//  blocks [64,320): q f32 -> bf16 conversion (qbf), fully coalesced.
// ---------------------------------------------------------------------------
__global__ __launch_bounds__(256) void prep_kernel(
    const float* __restrict__ sfi, const float* __restrict__ sf,
    const int* __restrict__ labels, const float* __restrict__ qf,
    float* __restrict__ partA, float* __restrict__ partB,
    float* __restrict__ pcnt, short* __restrict__ qbf) {
  const int t = threadIdx.x;

  if (blockIdx.x >= NBLK) {  // ---- q conversion: 128 rows per block ----
    const size_t cb = (size_t)(blockIdx.x - NBLK) * (128 * DD);
#pragma unroll
    for (int i = 0; i < 16; ++i) {
      const size_t off = cb + ((size_t)i * 256 + t) * 4;
      f32x4 f = *(const f32x4*)(qf + off);
      union { short4v s; uint32_t u[2]; } r;
      r.u[0] = pk2bf(f[0], f[1]);
      r.u[1] = pk2bf(f[2], f[3]);
      *(short4v*)(qbf + off) = r.s;
    }
    return;
  }

  // ---- centers partials ----
  __shared__ float accA[2][CC][DD];
  __shared__ float accB[2][CC][DD];
  __shared__ float cnt[2][CC];
  const int d = t & 127, s = t >> 7;
  for (int i = t; i < 2 * CC * DD; i += 256) {
    ((float*)accA)[i] = 0.f;
    ((float*)accB)[i] = 0.f;
  }
  if (t < 2 * CC) ((float*)cnt)[t] = 0.f;
  __syncthreads();

  const int base = blockIdx.x * (NS / NBLK);
  for (int i = s; i < NS / NBLK; i += 2) {
    const int r = base + i;
    const int lbl = labels[r];
    accA[s][lbl][d] += sfi[(size_t)r * DD + d];
    accB[s][lbl][d] += sf[(size_t)r * DD + d];
    if (d == 0) cnt[s][lbl] += 1.f;
  }
  __syncthreads();

  float* pa = partA + (size_t)blockIdx.x * (CC * DD);
  float* pb = partB + (size_t)blockIdx.x * (CC * DD);
  for (int i = t; i < CC * DD; i += 256) {
    pa[i] = ((float*)accA)[i] + ((float*)accA)[CC * DD + i];
    pb[i] = ((float*)accB)[i] + ((float*)accB)[CC * DD + i];
  }
  if (t < CC) pcnt[blockIdx.x * CC + t] = cnt[0][t] + cnt[1][t];
}

// ---------------------------------------------------------------------------
// Kernel 2: finalize centers + fused per-class weights in FRAGMENT order.
// 16B unit u within class c: u = w*256 + kb*64 + lane (w=0..7, kb=0..3)
//   holds WtT[j][e0..e0+7] bf16, j = w*16 + (lane&15), e0 = kb*32 + (lane>>4)*8
// grid=16 (c), block=256. (unchanged)
// ---------------------------------------------------------------------------
__global__ __launch_bounds__(256) void build_wt_kernel(
    const float* __restrict__ W1, const float* __restrict__ partA,
    const float* __restrict__ partB, const float* __restrict__ pcnt,
    float* __restrict__ sg_out, short* __restrict__ WtTg) {
  __shared__ float sgc[DD], prc[DD];
  const int c = blockIdx.x, t = threadIdx.x;

  float cnt = 0.f;
  for (int b = 0; b < NBLK; ++b) cnt += pcnt[b * CC + c];
  cnt = fmaxf(cnt, 1.f);
  if (t < 128) {
    float a = 0.f;
    for (int b = 0; b < NBLK; ++b) a += partA[(size_t)b * (CC * DD) + c * DD + t];
    const float m = a / cnt;
    const float s = 1.f / (1.f + expf(-m));
    sgc[t] = s;
    sg_out[c * DD + t] = s;
  } else {
    const int d = t - 128;
    float a = 0.f;
    for (int b = 0; b < NBLK; ++b) a += partB[(size_t)b * (CC * DD) + c * DD + d];
    prc[d] = a / cnt;
  }
  __syncthreads();

  for (int it = 0; it < 8; ++it) {
    const int u = it * 256 + t;
    const int w_ = u >> 8;
    const int kb = (u >> 6) & 3;
    const int lane = u & 63;
    const int j = w_ * 16 + (lane & 15);
    const int e0 = kb * 32 + (lane >> 4) * 8;
    short8 r;
#pragma unroll
    for (int rr = 0; rr < 8; ++rr) {
      const int e = e0 + rr;
      float v = W1[e * DD + j] + sgc[e] * W1[(DD + e) * DD + j] +
                prc[e] * W1[2 * DD * DD + j];
      r[rr] = f2bf(v);
    }
    *(short8*)(WtTg + ((size_t)c * 2048 + u) * 8) = r;
  }
}

// ---------------------------------------------------------------------------
// Kernel 3: main MFMA kernel. grid=512, block=512 (8 waves), 64 q per block,
// 2 blocks/CU (launch_bounds 512,4). Wave w: j rows [w*16,+16), all 64 q.
// Register plan fits 128 VGPR: bq 64 + wf dbuf 32 + 2 live acc 8 + misc.
// Per class: 4 coalesced W loads (L2) + 16 MFMA + interleaved fold ->
// p_part[w][c][q]; one barrier; sigmoid epilogue -> w_ws[q][16].
// ---------------------------------------------------------------------------
__global__ __launch_bounds__(512, 4) void main_kernel(
    const short* __restrict__ qbf, const short* __restrict__ WtTg,
    const float* __restrict__ b1, const float* __restrict__ W2,
    const float* __restrict__ b2, float* __restrict__ w_ws) {
  __shared__ float p_part[8][CC][64];  // 32 KiB

  const int tid = threadIdx.x;
  const int lane = tid & 63;
  const int w = tid >> 6;  // 0..7
  const int l15 = lane & 15, l4 = lane >> 4;
  const int qbase = blockIdx.x * 64;

  // ---- B fragments: direct bf16 loads (no conversion) ----
  short8 bq[4][4];
#pragma unroll
  for (int qn = 0; qn < 4; ++qn) {
    const short* qrow = qbf + (size_t)(qbase + qn * 16 + l15) * DD;
#pragma unroll
    for (int kb = 0; kb < 4; ++kb)
      bq[qn][kb] = *(const short8*)(qrow + kb * 32 + l4 * 8);
  }

  const f32x4 b1v = *(const f32x4*)(b1 + w * 16 + l4 * 4);
  const f32x4 w2v = *(const f32x4*)(W2 + w * 16 + l4 * 4);
  const float b2s = b2[0];

  const char* wbase = (const char*)WtTg + w * 4096 + lane * 16;

#define LOADW(dst, cls)                                                     \
  {                                                                         \
    _Pragma("unroll") for (int kb = 0; kb < 4; ++kb) dst[kb] =              \
        *(const short8*)(wbase + (size_t)(cls)*32768 + kb * 1024);          \
  }

#define COMPUTE(wf, cls)                                                    \
  {                                                                         \
    _Pragma("unroll") for (int qp = 0; qp < 2; ++qp) {                      \
      f32x4 a0 = b1v, a1 = b1v;                                             \
      _Pragma("unroll") for (int kb = 0; kb < 4; ++kb) {                    \
        a0 = __builtin_amdgcn_mfma_f32_16x16x32_bf16(wf[kb],                \
                                                     bq[2 * qp][kb], a0,    \
                                                     0, 0, 0);              \
        a1 = __builtin_amdgcn_mfma_f32_16x16x32_bf16(wf[kb],                \
                                                     bq[2 * qp + 1][kb],    \
                                                     a1, 0, 0, 0);          \
      }                                                                     \
      float p0 = 0.f, p1 = 0.f;                                             \
      _Pragma("unroll") for (int i = 0; i < 4; ++i) {                       \
        p0 += fmaxf(a0[i], 0.f) * w2v[i];                                   \
        p1 += fmaxf(a1[i], 0.f) * w2v[i];                                   \
      }                                                                     \
      p0 += __shfl_xor(p0, 16);                                             \
      p0 += __shfl_xor(p0, 32);                                             \
      p1 += __shfl_xor(p1, 16);                                             \
      p1 += __shfl_xor(p1, 32);                                             \
      if (l4 == 0) {                                                        \
        p_part[w][cls][(2 * qp) * 16 + l15] = p0;                           \
        p_part[w][cls][(2 * qp + 1) * 16 + l15] = p1;                       \
      }                                                                     \
    }                                                                       \
  }

  short8 wfA[4], wfB[4];
  LOADW(wfA, 0);
  for (int c = 0; c < CC; c += 2) {
    LOADW(wfB, c + 1);
    COMPUTE(wfA, c);
    if (c + 2 < CC) LOADW(wfA, c + 2);
    COMPUTE(wfB, c + 1);
  }
#undef LOADW
#undef COMPUTE

  __syncthreads();

  // ---- epilogue: thread (q = tid&63, cg = tid>>6) -> 2 classes ----
  {
    const int q = tid & 63;
    const int cg = tid >> 6;  // 0..7
    float s0 = 0.f, s1 = 0.f;
#pragma unroll
    for (int wv = 0; wv < 8; ++wv) {
      s0 += p_part[wv][cg * 2][q];
      s1 += p_part[wv][cg * 2 + 1][q];
    }
    float2 o;
    o.x = 1.f / (1.f + __expf(-(s0 + b2s)));
    o.y = 1.f / (1.f + __expf(-(s1 + b2s)));
    *(float2*)(w_ws + ((size_t)(qbase + q)) * 16 + cg * 2) = o;
  }
}

// ---------------------------------------------------------------------------
// Kernel 4: epilogue. grid=512, block=256. (unchanged)
// ---------------------------------------------------------------------------
__global__ __launch_bounds__(256) void agg_kernel(
    const float* __restrict__ qf, const float* __restrict__ sg,
    const float* __restrict__ w_ws, float* __restrict__ out) {
  const int t = threadIdx.x;
  const int s = t >> 5;
  const int ec = t & 31;
  const int e0 = ec * 4;
  const int qbase = blockIdx.x * 64;

  float4 sgv[16];
#pragma unroll
  for (int c = 0; c < 16; ++c) sgv[c] = *(const float4*)(sg + c * DD + e0);

  for (int qi = 0; qi < 8; ++qi) {
    const int q = qbase + qi * 8 + s;
    const float* wr = w_ws + (size_t)q * 16;
    float4 w0 = *(const float4*)(wr);
    float4 w1 = *(const float4*)(wr + 4);
    float4 w2 = *(const float4*)(wr + 8);
    float4 w3 = *(const float4*)(wr + 12);
    const float wc[16] = {w0.x, w0.y, w0.z, w0.w, w1.x, w1.y, w1.z, w1.w,
                          w2.x, w2.y, w2.z, w2.w, w3.x, w3.y, w3.z, w3.w};
    float Sv = 0.f;
#pragma unroll
    for (int c = 0; c < 16; ++c) Sv += wc[c];

    f32x4 sgw = {0.f, 0.f, 0.f, 0.f};
#pragma unroll
    for (int c = 0; c < 16; ++c) {
      sgw.x += wc[c] * sgv[c].x;
      sgw.y += wc[c] * sgv[c].y;
      sgw.z += wc[c] * sgv[c].z;
      sgw.w += wc[c] * sgv[c].w;
    }

    const float* qrow = qf + (size_t)q * DD;
    float4 qa = *(const float4*)(qrow + e0);
    float2 qd = *(const float2*)(qrow + 2 * ec);
    float2 qu = *(const float2*)(qrow + 64 + 2 * ec);

    float2 lo, hi;
    lo.x = 0.5f * (qa.x + qa.y) * Sv + qd.x;
    lo.y = 0.5f * (qa.z + qa.w) * Sv + qd.y;
    hi.x = 0.5f * (qa.x * sgw.x + qa.y * sgw.y) + qu.x;
    hi.y = 0.5f * (qa.z * sgw.z + qa.w * sgw.w) + qu.y;

    float* orow = out + (size_t)q * DD;
    *(float2*)(orow + 2 * ec) = lo;
    *(float2*)(orow + 64 + 2 * ec) = hi;
  }
}

// ---------------------------------------------------------------------------
extern "C" void kernel_launch(void* const* d_in, const int* in_sizes, int n_in,
                              void* d_out, int out_size, void* d_ws, size_t ws_size,
                              hipStream_t stream) {
  const float* sfi = (const float*)d_in[0];
  const float* sf  = (const float*)d_in[1];
  const float* qf  = (const float*)d_in[2];
  const float* W1  = (const float*)d_in[3];
  const float* b1  = (const float*)d_in[4];
  const float* W2  = (const float*)d_in[5];
  const float* b2  = (const float*)d_in[6];
  const int* slab  = (const int*)d_in[7];
  float* out = (float*)d_out;

  float* sg    = (float*)d_ws;                       // 2048 f
  float* w_ws  = sg + CC * DD;                       // 524288 f  [q][16]
  short* WtTg  = (short*)(w_ws + (size_t)QQ * CC);   // 262144 shorts (512 KB)
  float* partA = (float*)(WtTg + CC * DD * DD);      // 64*2048 f
  float* partB = partA + NBLK * CC * DD;             // 64*2048 f
  float* pcnt  = partB + NBLK * CC * DD;             // 64*16 f
  short* qbf   = (short*)(pcnt + NBLK * CC);         // QQ*DD shorts (8 MB)

  prep_kernel<<<NBLK + QQ / 128, 256, 0, stream>>>(sfi, sf, slab, qf, partA,
                                                   partB, pcnt, qbf);
  build_wt_kernel<<<CC, 256, 0, stream>>>(W1, partA, partB, pcnt, sg, WtTg);
  main_kernel<<<QQ / 64, 512, 0, stream>>>(qbf, WtTg, b1, W2, b2, w_ws);
  agg_kernel<<<QQ / 64, 256, 0, stream>>>(qf, sg, w_ws, out);
}